// Round 1
// baseline (400.864 us; speedup 1.0000x reference)
//
#include <hip/hip_runtime.h>

#define M_TOT 65536   // B*V
#define K_TOT 1024    // F
#define N_TOT 1024    // U
#define BM 128
#define BN 128
#define BK 32

typedef __attribute__((ext_vector_type(4))) unsigned int u32x4;
typedef __attribute__((ext_vector_type(4))) float f32x4;
typedef __attribute__((ext_vector_type(8))) __bf16 bf16x8;

static __device__ __forceinline__ unsigned short f2bf(float f) {
    unsigned int u = __float_as_uint(f);
    u += 0x7fffu + ((u >> 16) & 1u);   // round-to-nearest-even
    return (unsigned short)(u >> 16);
}

// ---- prep 1: valid[row] = any(adj[row*128 .. +128) >= 0), one wave per row ----
__global__ __launch_bounds__(256) void valid_kernel(const int* __restrict__ adj,
                                                    unsigned char* __restrict__ valid) {
    const int row  = blockIdx.x * 4 + (threadIdx.x >> 6);
    const int lane = threadIdx.x & 63;
    const int2 v = reinterpret_cast<const int2*>(adj)[(size_t)row * 64 + lane];
    const int anyv = __any((v.x >= 0) || (v.y >= 0));
    if (lane == 0) valid[row] = anyv ? 1 : 0;
}

// ---- prep 2: kT[n][k] = bf16(kern[k][n]), tiled 32x32 transpose ----
__global__ __launch_bounds__(256) void transposeB_kernel(const float* __restrict__ kern,
                                                         unsigned short* __restrict__ kT) {
    __shared__ float tile[32][33];
    const int bx = blockIdx.x & 31;   // n tile
    const int by = blockIdx.x >> 5;   // k tile
    const int tx = threadIdx.x & 31;
    const int ty = threadIdx.x >> 5;  // 0..7
#pragma unroll
    for (int r = 0; r < 4; ++r)
        tile[ty + r * 8][tx] = kern[(size_t)(by * 32 + ty + r * 8) * N_TOT + bx * 32 + tx];
    __syncthreads();
#pragma unroll
    for (int r = 0; r < 4; ++r)
        kT[(size_t)(bx * 32 + ty + r * 8) * K_TOT + by * 32 + tx] = f2bf(tile[tx][ty + r * 8]);
}

// ---- main: C = relu(A*B + bias) where valid, else A passthrough ----
// A: [M,K] fp32 (features), Bt: [N,K] bf16 bits (pre-transposed kernel)
__global__ __launch_bounds__(256) void gemm_kernel(
    const float* __restrict__ A,
    const unsigned short* __restrict__ Bt,
    const float* __restrict__ bias,
    const unsigned char* __restrict__ valid,
    float* __restrict__ out)
{
    __shared__ __align__(16) unsigned short Asm[2][BM * BK];
    __shared__ __align__(16) unsigned short Bsm[2][BN * BK];

    const int tid = threadIdx.x;
    const int bm = blockIdx.x >> 3;          // 8 N-blocks share an A panel (L2 reuse)
    const int bn = blockIdx.x & 7;
    const size_t m0 = (size_t)bm * BM;
    const int n0 = bn * BN;

    // A staging: thread covers 8B unit ja (4 floats) of row ra0 + t*32, t=0..3
    const int ja  = tid & 7;
    const int ra0 = tid >> 3;
    // B staging: thread covers 16B chunk jb (8 bf16) of row rb0 + t*64, t=0..1
    const int jb  = tid & 3;
    const int rb0 = tid >> 2;

    const int wv   = tid >> 6;
    const int wr   = wv >> 1;   // wave row (0..1), 64 rows each
    const int wc   = wv & 1;    // wave col (0..1), 64 cols each
    const int lane = tid & 63;
    const int lr   = lane & 15;
    const int g    = lane >> 4;

    f32x4 acc[4][4];
#pragma unroll
    for (int m = 0; m < 4; ++m)
#pragma unroll
        for (int n = 0; n < 4; ++n)
            acc[m][n] = {0.0f, 0.0f, 0.0f, 0.0f};

    // LDS indices (ushort units). Swizzle: physical16Bchunk = logical ^ ((row>>1)&3)
    int awidx[4], bwidx[2], aridx[4], bridx[4];
#pragma unroll
    for (int t = 0; t < 4; ++t) {
        const int row = ra0 + t * 32;
        awidx[t] = row * 32 + (((ja >> 1) ^ ((row >> 1) & 3)) * 8) + (ja & 1) * 4;
    }
#pragma unroll
    for (int t = 0; t < 2; ++t) {
        const int row = rb0 + t * 64;
        bwidx[t] = row * 32 + ((jb ^ ((row >> 1) & 3)) * 8);
    }
#pragma unroll
    for (int m = 0; m < 4; ++m) {
        const int row = wr * 64 + m * 16 + lr;
        aridx[m] = row * 32 + ((g ^ ((row >> 1) & 3)) * 8);
    }
#pragma unroll
    for (int n = 0; n < 4; ++n) {
        const int row = wc * 64 + n * 16 + lr;
        bridx[n] = row * 32 + ((g ^ ((row >> 1) & 3)) * 8);
    }

    const int NT = K_TOT / BK;   // 32
    f32x4 areg[4];
    u32x4 breg[2];

    // prologue: tile 0 -> buf 0
#pragma unroll
    for (int t = 0; t < 4; ++t)
        areg[t] = reinterpret_cast<const f32x4*>(A + (m0 + ra0 + t * 32) * K_TOT)[ja];
#pragma unroll
    for (int t = 0; t < 2; ++t)
        breg[t] = reinterpret_cast<const u32x4*>(Bt + (size_t)(n0 + rb0 + t * 64) * K_TOT)[jb];
#pragma unroll
    for (int t = 0; t < 4; ++t) {
        unsigned long long w =
            (unsigned long long)f2bf(areg[t][0]) |
            ((unsigned long long)f2bf(areg[t][1]) << 16) |
            ((unsigned long long)f2bf(areg[t][2]) << 32) |
            ((unsigned long long)f2bf(areg[t][3]) << 48);
        *reinterpret_cast<unsigned long long*>(&Asm[0][awidx[t]]) = w;
    }
#pragma unroll
    for (int t = 0; t < 2; ++t)
        *reinterpret_cast<u32x4*>(&Bsm[0][bwidx[t]]) = breg[t];

    int cur = 0;
    for (int kt = 0; kt < NT; ++kt) {
        const bool more = (kt + 1) < NT;
        if (more) {
            const int koff = (kt + 1) * BK;
#pragma unroll
            for (int t = 0; t < 4; ++t)
                areg[t] = reinterpret_cast<const f32x4*>(A + (m0 + ra0 + t * 32) * K_TOT + koff)[ja];
#pragma unroll
            for (int t = 0; t < 2; ++t)
                breg[t] = reinterpret_cast<const u32x4*>(Bt + (size_t)(n0 + rb0 + t * 64) * K_TOT + koff)[jb];
        }
        __syncthreads();   // buf[cur] writes visible; prev-iter reads of buf[cur^1] done
        bf16x8 af[4], bfr[4];
#pragma unroll
        for (int m = 0; m < 4; ++m)
            af[m] = __builtin_bit_cast(bf16x8, *reinterpret_cast<const u32x4*>(&Asm[cur][aridx[m]]));
#pragma unroll
        for (int n = 0; n < 4; ++n)
            bfr[n] = __builtin_bit_cast(bf16x8, *reinterpret_cast<const u32x4*>(&Bsm[cur][bridx[n]]));
#pragma unroll
        for (int m = 0; m < 4; ++m)
#pragma unroll
            for (int n = 0; n < 4; ++n)
                acc[m][n] = __builtin_amdgcn_mfma_f32_16x16x32_bf16(af[m], bfr[n], acc[m][n], 0, 0, 0);
        if (more) {
            const int nxt = cur ^ 1;
#pragma unroll
            for (int t = 0; t < 4; ++t) {
                unsigned long long w =
                    (unsigned long long)f2bf(areg[t][0]) |
                    ((unsigned long long)f2bf(areg[t][1]) << 16) |
                    ((unsigned long long)f2bf(areg[t][2]) << 32) |
                    ((unsigned long long)f2bf(areg[t][3]) << 48);
                *reinterpret_cast<unsigned long long*>(&Asm[nxt][awidx[t]]) = w;
            }
#pragma unroll
            for (int t = 0; t < 2; ++t)
                *reinterpret_cast<u32x4*>(&Bsm[nxt][bwidx[t]]) = breg[t];
        }
        cur ^= 1;
    }

    // epilogue: C/D layout col = lane&15, row = (lane>>4)*4 + reg
    float bv[4];
#pragma unroll
    for (int n = 0; n < 4; ++n)
        bv[n] = bias[n0 + wc * 64 + n * 16 + lr];

#pragma unroll
    for (int m = 0; m < 4; ++m) {
#pragma unroll
        for (int q = 0; q < 4; ++q) {
            const size_t row = m0 + wr * 64 + m * 16 + g * 4 + q;
            const bool v = valid[row] != 0;
            const size_t ro = row * (size_t)N_TOT;
#pragma unroll
            for (int n = 0; n < 4; ++n) {
                const int col = n0 + wc * 64 + n * 16 + lr;
                float r;
                if (v) r = fmaxf(acc[m][n][q] + bv[n], 0.0f);
                else   r = A[ro + col];   // K_TOT == N_TOT: same offset
                out[ro + col] = r;
            }
        }
    }
}

extern "C" void kernel_launch(void* const* d_in, const int* in_sizes, int n_in,
                              void* d_out, int out_size, void* d_ws, size_t ws_size,
                              hipStream_t stream) {
    const int*   adj  = (const int*)d_in[0];
    const float* feat = (const float*)d_in[1];
    const float* kern = (const float*)d_in[2];
    const float* bias = (const float*)d_in[3];
    float* out = (float*)d_out;

    unsigned short* kT    = (unsigned short*)d_ws;                      // 2 MB
    unsigned char*  valid = (unsigned char*)d_ws + 2 * 1024 * 1024;     // 64 KB

    valid_kernel<<<M_TOT / 4, 256, 0, stream>>>(adj, valid);
    transposeB_kernel<<<(K_TOT / 32) * (N_TOT / 32), 256, 0, stream>>>(kern, kT);
    gemm_kernel<<<(M_TOT / BM) * (N_TOT / BN), 256, 0, stream>>>(feat, kT, bias, valid, out);
}

// Round 2
// 327.827 us; speedup vs baseline: 1.2228x; 1.2228x over previous
//
#include <hip/hip_runtime.h>

#define MTOT 65536   // B*V
#define KTOT 1024    // F
#define NTOT 1024    // U
#define BM 128
#define BN 128
#define BK 32

typedef __attribute__((ext_vector_type(4))) unsigned int u32x4;
typedef __attribute__((ext_vector_type(4))) float f32x4;
typedef __attribute__((ext_vector_type(8))) __bf16 bf16x8;
typedef __attribute__((ext_vector_type(4))) unsigned short u16x4;

static __device__ __forceinline__ unsigned short f2bf(float f) {
    unsigned int u = __float_as_uint(f);
    u += 0x7fffu + ((u >> 16) & 1u);   // round-to-nearest-even
    return (unsigned short)(u >> 16);
}

#define GLOAD16(g, l)                                                              \
    __builtin_amdgcn_global_load_lds(                                              \
        (const __attribute__((address_space(1))) void*)(g),                        \
        (__attribute__((address_space(3))) void*)(l), 16, 0, 0)

// ---- prep: valid + fp32->bf16 feature convert + invalid-row passthrough ----
// one wave per row
__global__ __launch_bounds__(256) void prep_kernel(const int* __restrict__ adj,
                                                   const float* __restrict__ feat,
                                                   unsigned short* __restrict__ abf,
                                                   unsigned char* __restrict__ valid,
                                                   float* __restrict__ out) {
    const int row  = blockIdx.x * 4 + (threadIdx.x >> 6);
    const int lane = threadIdx.x & 63;
    const int2 a2  = reinterpret_cast<const int2*>(adj)[(size_t)row * 64 + lane];
    const bool anyv = __any((a2.x >= 0) || (a2.y >= 0)) != 0;

    const f32x4* frow = reinterpret_cast<const f32x4*>(feat + (size_t)row * KTOT);
    u16x4*       brow = reinterpret_cast<u16x4*>(abf + (size_t)row * KTOT);
    f32x4*       orow = reinterpret_cast<f32x4*>(out + (size_t)row * NTOT);
#pragma unroll
    for (int i = 0; i < 4; ++i) {
        const f32x4 v = frow[lane + 64 * i];
        u16x4 b;
        b.x = f2bf(v[0]); b.y = f2bf(v[1]); b.z = f2bf(v[2]); b.w = f2bf(v[3]);
        brow[lane + 64 * i] = b;
        if (!anyv) orow[lane + 64 * i] = v;   // K==N: invalid rows pass features through
    }
    if (lane == 0) valid[row] = anyv ? 1 : 0;
}

// ---- prep 2: kT[n][k] = bf16(kern[k][n]) ----
__global__ __launch_bounds__(256) void transposeB_kernel(const float* __restrict__ kern,
                                                         unsigned short* __restrict__ kT) {
    __shared__ float tile[32][33];
    const int bx = blockIdx.x & 31;
    const int by = blockIdx.x >> 5;
    const int tx = threadIdx.x & 31;
    const int ty = threadIdx.x >> 5;
#pragma unroll
    for (int r = 0; r < 4; ++r)
        tile[ty + r * 8][tx] = kern[(size_t)(by * 32 + ty + r * 8) * NTOT + bx * 32 + tx];
    __syncthreads();
#pragma unroll
    for (int r = 0; r < 4; ++r)
        kT[(size_t)(bx * 32 + ty + r * 8) * KTOT + by * 32 + tx] = f2bf(tile[tx][ty + r * 8]);
}

// ---- main GEMM (m97 template): A bf16 [M][K], Bt bf16 [N][K], gload_lds staging ----
__global__ __launch_bounds__(256) void gemm_kernel(const unsigned short* __restrict__ A,
                                                   const unsigned short* __restrict__ Bt,
                                                   const float* __restrict__ bias,
                                                   const unsigned char* __restrict__ valid,
                                                   float* __restrict__ out) {
    __shared__ __align__(16) unsigned short Asm[2][BM * BK];
    __shared__ __align__(16) unsigned short Bsm[2][BN * BK];

    const int tid  = threadIdx.x;
    const int lane = tid & 63;
    const int wv   = tid >> 6;

    // bijective XCD swizzle: nwg=4096 -> XCD k owns bm in [k*64, k*64+64), bn consecutive
    const int cpx = (int)gridDim.x >> 3;
    const int swz = (blockIdx.x & 7) * cpx + (blockIdx.x >> 3);
    const int bm  = swz >> 3;
    const int bn  = swz & 7;
    const size_t m0 = (size_t)bm * BM;
    const int    n0 = bn * BN;

    // staging: per-lane global source is chunk-permuted, LDS dest linear (rule #21)
    const int srow = lane >> 2;   // row within 16-row slot
    const int pch  = lane & 3;    // physical 16B chunk within 64B row

    // fragment read addressing (XOR matches the source permutation)
    const int lr = lane & 15;
    const int g4 = lane >> 4;
    const int wr = wv >> 1;       // wave row (0..1)
    const int wc = wv & 1;        // wave col (0..1)

    int aridx[4], bridx[4];
#pragma unroll
    for (int m = 0; m < 4; ++m) {
        const int row = wr * 64 + m * 16 + lr;
        aridx[m] = row * BK + ((g4 ^ ((row >> 1) & 3)) << 3);
    }
#pragma unroll
    for (int n = 0; n < 4; ++n) {
        const int row = wc * 64 + n * 16 + lr;
        bridx[n] = row * BK + ((g4 ^ ((row >> 1) & 3)) << 3);
    }

    f32x4 acc[4][4];
#pragma unroll
    for (int m = 0; m < 4; ++m)
#pragma unroll
        for (int n = 0; n < 4; ++n)
            acc[m][n] = {0.0f, 0.0f, 0.0f, 0.0f};

    const unsigned short* Abase = A + m0 * (size_t)KTOT;
    const unsigned short* Bbase = Bt + (size_t)n0 * KTOT;

    auto stage = [&](int buf, int kt) {
#pragma unroll
        for (int i = 0; i < 2; ++i) {
            const int slot = i * 4 + wv;              // 0..7, 16 rows each
            const int row  = slot * 16 + srow;
            const int lch  = pch ^ ((row >> 1) & 3);  // logical chunk at this physical slot
            GLOAD16(Abase + (size_t)row * KTOT + kt * BK + lch * 8, &Asm[buf][slot * 512]);
            GLOAD16(Bbase + (size_t)row * KTOT + kt * BK + lch * 8, &Bsm[buf][slot * 512]);
        }
    };

    stage(0, 0);
    __syncthreads();

    int cur = 0;
    const int NSTEP = KTOT / BK;   // 32
    for (int kt = 0; kt < NSTEP; ++kt) {
        if (kt + 1 < NSTEP) stage(cur ^ 1, kt + 1);   // async next-tile loads in flight
        bf16x8 af[4], bfr[4];
#pragma unroll
        for (int m = 0; m < 4; ++m)
            af[m] = __builtin_bit_cast(bf16x8, *reinterpret_cast<const u32x4*>(&Asm[cur][aridx[m]]));
#pragma unroll
        for (int n = 0; n < 4; ++n)
            bfr[n] = __builtin_bit_cast(bf16x8, *reinterpret_cast<const u32x4*>(&Bsm[cur][bridx[n]]));
#pragma unroll
        for (int m = 0; m < 4; ++m)
#pragma unroll
            for (int n = 0; n < 4; ++n)
                acc[m][n] = __builtin_amdgcn_mfma_f32_16x16x32_bf16(af[m], bfr[n], acc[m][n], 0, 0, 0);
        __syncthreads();   // drains vmcnt (stage done) + lgkmcnt, one barrier per K-step
        cur ^= 1;
    }

    // epilogue: C/D layout col=lane&15, row=(lane>>4)*4+q ; store valid rows only
    float bv[4];
#pragma unroll
    for (int n = 0; n < 4; ++n)
        bv[n] = bias[n0 + wc * 64 + n * 16 + lr];

#pragma unroll
    for (int m = 0; m < 4; ++m) {
#pragma unroll
        for (int q = 0; q < 4; ++q) {
            const size_t row = m0 + wr * 64 + m * 16 + g4 * 4 + q;
            if (valid[row]) {
                const size_t ro = row * NTOT + n0 + wc * 64 + lr;
#pragma unroll
                for (int n = 0; n < 4; ++n)
                    out[ro + n * 16] = fmaxf(acc[m][n][q] + bv[n], 0.0f);
            }
        }
    }
}

// ================= fallback path (round-1 kernels, ws too small) =================
__global__ __launch_bounds__(256) void valid_kernel(const int* __restrict__ adj,
                                                    unsigned char* __restrict__ valid) {
    const int row  = blockIdx.x * 4 + (threadIdx.x >> 6);
    const int lane = threadIdx.x & 63;
    const int2 v = reinterpret_cast<const int2*>(adj)[(size_t)row * 64 + lane];
    const int anyv = __any((v.x >= 0) || (v.y >= 0));
    if (lane == 0) valid[row] = anyv ? 1 : 0;
}

__global__ __launch_bounds__(256) void gemm_fb(const float* __restrict__ A,
                                               const unsigned short* __restrict__ Bt,
                                               const float* __restrict__ bias,
                                               const unsigned char* __restrict__ valid,
                                               float* __restrict__ out) {
    __shared__ __align__(16) unsigned short Asm[2][BM * BK];
    __shared__ __align__(16) unsigned short Bsm[2][BN * BK];
    const int tid = threadIdx.x;
    const int bm = blockIdx.x >> 3;
    const int bn = blockIdx.x & 7;
    const size_t m0 = (size_t)bm * BM;
    const int n0 = bn * BN;
    const int ja = tid & 7, ra0 = tid >> 3;
    const int jb = tid & 3, rb0 = tid >> 2;
    const int wv = tid >> 6, wr = wv >> 1, wc = wv & 1;
    const int lane = tid & 63, lr = lane & 15, g = lane >> 4;
    f32x4 acc[4][4];
#pragma unroll
    for (int m = 0; m < 4; ++m)
#pragma unroll
        for (int n = 0; n < 4; ++n) acc[m][n] = {0.f, 0.f, 0.f, 0.f};
    int awidx[4], bwidx[2], aridx[4], bridx[4];
#pragma unroll
    for (int t = 0; t < 4; ++t) {
        const int row = ra0 + t * 32;
        awidx[t] = row * 32 + (((ja >> 1) ^ ((row >> 1) & 3)) * 8) + (ja & 1) * 4;
    }
#pragma unroll
    for (int t = 0; t < 2; ++t) {
        const int row = rb0 + t * 64;
        bwidx[t] = row * 32 + ((jb ^ ((row >> 1) & 3)) * 8);
    }
#pragma unroll
    for (int m = 0; m < 4; ++m) {
        const int row = wr * 64 + m * 16 + lr;
        aridx[m] = row * 32 + ((g ^ ((row >> 1) & 3)) * 8);
    }
#pragma unroll
    for (int n = 0; n < 4; ++n) {
        const int row = wc * 64 + n * 16 + lr;
        bridx[n] = row * 32 + ((g ^ ((row >> 1) & 3)) * 8);
    }
    const int NT = KTOT / BK;
    f32x4 areg[4];
    u32x4 breg[2];
#pragma unroll
    for (int t = 0; t < 4; ++t)
        areg[t] = reinterpret_cast<const f32x4*>(A + (m0 + ra0 + t * 32) * KTOT)[ja];
#pragma unroll
    for (int t = 0; t < 2; ++t)
        breg[t] = reinterpret_cast<const u32x4*>(Bt + (size_t)(n0 + rb0 + t * 64) * KTOT)[jb];
#pragma unroll
    for (int t = 0; t < 4; ++t) {
        unsigned long long w = (unsigned long long)f2bf(areg[t][0]) |
                               ((unsigned long long)f2bf(areg[t][1]) << 16) |
                               ((unsigned long long)f2bf(areg[t][2]) << 32) |
                               ((unsigned long long)f2bf(areg[t][3]) << 48);
        *reinterpret_cast<unsigned long long*>(&Asm[0][awidx[t]]) = w;
    }
#pragma unroll
    for (int t = 0; t < 2; ++t) *reinterpret_cast<u32x4*>(&Bsm[0][bwidx[t]]) = breg[t];
    int cur = 0;
    for (int kt = 0; kt < NT; ++kt) {
        const bool more = (kt + 1) < NT;
        if (more) {
            const int koff = (kt + 1) * BK;
#pragma unroll
            for (int t = 0; t < 4; ++t)
                areg[t] = reinterpret_cast<const f32x4*>(A + (m0 + ra0 + t * 32) * KTOT + koff)[ja];
#pragma unroll
            for (int t = 0; t < 2; ++t)
                breg[t] = reinterpret_cast<const u32x4*>(Bt + (size_t)(n0 + rb0 + t * 64) * KTOT + koff)[jb];
        }
        __syncthreads();
        bf16x8 af[4], bfr[4];
#pragma unroll
        for (int m = 0; m < 4; ++m)
            af[m] = __builtin_bit_cast(bf16x8, *reinterpret_cast<const u32x4*>(&Asm[cur][aridx[m]]));
#pragma unroll
        for (int n = 0; n < 4; ++n)
            bfr[n] = __builtin_bit_cast(bf16x8, *reinterpret_cast<const u32x4*>(&Bsm[cur][bridx[n]]));
#pragma unroll
        for (int m = 0; m < 4; ++m)
#pragma unroll
            for (int n = 0; n < 4; ++n)
                acc[m][n] = __builtin_amdgcn_mfma_f32_16x16x32_bf16(af[m], bfr[n], acc[m][n], 0, 0, 0);
        if (more) {
            const int nxt = cur ^ 1;
#pragma unroll
            for (int t = 0; t < 4; ++t) {
                unsigned long long w = (unsigned long long)f2bf(areg[t][0]) |
                                       ((unsigned long long)f2bf(areg[t][1]) << 16) |
                                       ((unsigned long long)f2bf(areg[t][2]) << 32) |
                                       ((unsigned long long)f2bf(areg[t][3]) << 48);
                *reinterpret_cast<unsigned long long*>(&Asm[nxt][awidx[t]]) = w;
            }
#pragma unroll
            for (int t = 0; t < 2; ++t) *reinterpret_cast<u32x4*>(&Bsm[nxt][bwidx[t]]) = breg[t];
        }
        cur ^= 1;
    }
    float bv[4];
#pragma unroll
    for (int n = 0; n < 4; ++n) bv[n] = bias[n0 + wc * 64 + n * 16 + lr];
#pragma unroll
    for (int m = 0; m < 4; ++m) {
#pragma unroll
        for (int q = 0; q < 4; ++q) {
            const size_t row = m0 + wr * 64 + m * 16 + g * 4 + q;
            const bool v = valid[row] != 0;
            const size_t ro = row * (size_t)NTOT;
#pragma unroll
            for (int n = 0; n < 4; ++n) {
                const int col = n0 + wc * 64 + n * 16 + lr;
                out[ro + col] = v ? fmaxf(acc[m][n][q] + bv[n], 0.0f) : A[ro + col];
            }
        }
    }
}

extern "C" void kernel_launch(void* const* d_in, const int* in_sizes, int n_in,
                              void* d_out, int out_size, void* d_ws, size_t ws_size,
                              hipStream_t stream) {
    const int*   adj  = (const int*)d_in[0];
    const float* feat = (const float*)d_in[1];
    const float* kern = (const float*)d_in[2];
    const float* bias = (const float*)d_in[3];
    float* out = (float*)d_out;

    unsigned short* kT    = (unsigned short*)d_ws;                             // 2 MB
    unsigned char*  valid = (unsigned char*)d_ws + 2 * 1024 * 1024;            // 64 KB
    unsigned short* abf   = (unsigned short*)((char*)d_ws + 2 * 1024 * 1024 + 65536);

    const size_t need = 2ull * 1024 * 1024 + 65536 + (size_t)MTOT * KTOT * 2;

    transposeB_kernel<<<(KTOT / 32) * (NTOT / 32), 256, 0, stream>>>(kern, kT);
    if (ws_size >= need) {
        prep_kernel<<<MTOT / 4, 256, 0, stream>>>(adj, feat, abf, valid, out);
        gemm_kernel<<<(MTOT / BM) * (NTOT / BN), 256, 0, stream>>>(abf, kT, bias, valid, out);
    } else {
        valid_kernel<<<MTOT / 4, 256, 0, stream>>>(adj, valid);
        gemm_fb<<<(MTOT / BM) * (NTOT / BN), 256, 0, stream>>>(feat, kT, bias, valid, out);
    }
}

// Round 3
// 265.908 us; speedup vs baseline: 1.5075x; 1.2329x over previous
//
#include <hip/hip_runtime.h>

#define MTOT 65536   // B*V
#define KTOT 1024    // F
#define NTOT 1024    // U

// main gemm tile
#define BM 256
#define BN 256
#define BK 32
#define NSTEP (KTOT / BK)   // 32

typedef __attribute__((ext_vector_type(4))) unsigned int u32x4;
typedef __attribute__((ext_vector_type(4))) float f32x4;
typedef __attribute__((ext_vector_type(8))) __bf16 bf16x8;
typedef __attribute__((ext_vector_type(4))) unsigned short u16x4;

static __device__ __forceinline__ unsigned short f2bf(float f) {
    unsigned int u = __float_as_uint(f);
    u += 0x7fffu + ((u >> 16) & 1u);   // round-to-nearest-even
    return (unsigned short)(u >> 16);
}

#define GLOAD16(g, l)                                                              \
    __builtin_amdgcn_global_load_lds(                                              \
        (const __attribute__((address_space(1))) void*)(g),                        \
        (__attribute__((address_space(3))) void*)(l), 16, 0, 0)

#define VMCNT(n) asm volatile("s_waitcnt vmcnt(" #n ")" ::: "memory")
#define BAR()    __builtin_amdgcn_s_barrier()

// ---- prep: valid + fp32->bf16 feature convert + invalid-row passthrough ----
__global__ __launch_bounds__(256) void prep_kernel(const int* __restrict__ adj,
                                                   const float* __restrict__ feat,
                                                   unsigned short* __restrict__ abf,
                                                   unsigned char* __restrict__ valid,
                                                   float* __restrict__ out) {
    const int row  = blockIdx.x * 4 + (threadIdx.x >> 6);
    const int lane = threadIdx.x & 63;
    const int2 a2  = reinterpret_cast<const int2*>(adj)[(size_t)row * 64 + lane];
    const bool anyv = __any((a2.x >= 0) || (a2.y >= 0)) != 0;

    const f32x4* frow = reinterpret_cast<const f32x4*>(feat + (size_t)row * KTOT);
    u16x4*       brow = reinterpret_cast<u16x4*>(abf + (size_t)row * KTOT);
    f32x4*       orow = reinterpret_cast<f32x4*>(out + (size_t)row * NTOT);
    if (anyv) {
#pragma unroll
        for (int i = 0; i < 4; ++i) {
            const f32x4 v = frow[lane + 64 * i];
            u16x4 b;
            b.x = f2bf(v[0]); b.y = f2bf(v[1]); b.z = f2bf(v[2]); b.w = f2bf(v[3]);
            brow[lane + 64 * i] = b;
        }
    } else {
#pragma unroll
        for (int i = 0; i < 4; ++i)
            orow[lane + 64 * i] = frow[lane + 64 * i];   // K==N passthrough
    }
    if (lane == 0) valid[row] = anyv ? 1 : 0;
}

// ---- prep 2: kT[n][k] = bf16(kern[k][n]) ----
__global__ __launch_bounds__(256) void transposeB_kernel(const float* __restrict__ kern,
                                                         unsigned short* __restrict__ kT) {
    __shared__ float tile[32][33];
    const int bx = blockIdx.x & 31;
    const int by = blockIdx.x >> 5;
    const int tx = threadIdx.x & 31;
    const int ty = threadIdx.x >> 5;
#pragma unroll
    for (int r = 0; r < 4; ++r)
        tile[ty + r * 8][tx] = kern[(size_t)(by * 32 + ty + r * 8) * NTOT + bx * 32 + tx];
    __syncthreads();
#pragma unroll
    for (int r = 0; r < 4; ++r)
        kT[(size_t)(bx * 32 + ty + r * 8) * KTOT + by * 32 + tx] = f2bf(tile[tx][ty + r * 8]);
}

// ---- main GEMM: 256x256 tile, quad-buffered counted-vmcnt pipeline ----
// A bf16 [M][K], Bt bf16 [N][K]. 512 threads = 8 waves (2M x 4N), 128 KiB LDS.
__global__ __launch_bounds__(512, 2) void gemm_kernel(const unsigned short* __restrict__ A,
                                                      const unsigned short* __restrict__ Bt,
                                                      const float* __restrict__ bias,
                                                      const unsigned char* __restrict__ valid,
                                                      float* __restrict__ out) {
    __shared__ __align__(16) unsigned short Asm[4][BM * BK];   // 4 x 16 KiB
    __shared__ __align__(16) unsigned short Bsm[4][BN * BK];   // 4 x 16 KiB

    const int tid  = threadIdx.x;
    const int lane = tid & 63;
    const int wv   = tid >> 6;     // 0..7
    const int wm   = wv >> 2;      // wave M half (0..1) -> rows wm*128..+128
    const int wn   = wv & 3;       // wave N quarter (0..3) -> cols wn*64..+64

    // bijective XCD swizzle (nwg = 1024, divisible by 8)
    const int cpx = (int)gridDim.x >> 3;
    const int swz = ((int)blockIdx.x & 7) * cpx + ((int)blockIdx.x >> 3);
    const int bm  = swz >> 2;      // 0..255
    const int bn  = swz & 3;       // 0..3
    const size_t m0 = (size_t)bm * BM;
    const int    n0 = bn * BN;

    // ---- staging addressing (rule #21: linear LDS dest, inverse-permuted source) ----
    // thread covers 16B chunk (tid&3) of tile row (tid>>2) (+128 for i=1)
    const int srow = tid >> 2;                        // 0..127
    const int lch  = (tid & 3) ^ ((tid >> 3) & 3);    // source chunk for this phys slot
    const unsigned short* Abase = A  + m0 * (size_t)KTOT;
    const unsigned short* Bbase = Bt + (size_t)n0 * KTOT;
    const size_t aoff = (size_t)srow * KTOT + lch * 8;    // ushort units
    const int    ldst = (wv << 4) * BK;                   // wave-uniform LDS base (ushort)

    // ---- fragment read addressing (XOR matches source permutation) ----
    const int lr  = lane & 15;
    const int g4  = lane >> 4;
    const int rch = (g4 ^ ((lr >> 1) & 3)) << 3;          // swizzled 16B chunk, ushort units
    int aridx[8], bridx[4];
#pragma unroll
    for (int m = 0; m < 8; ++m)
        aridx[m] = (wm * 128 + m * 16 + lr) * BK + rch;
#pragma unroll
    for (int n = 0; n < 4; ++n)
        bridx[n] = (wn * 64 + n * 16 + lr) * BK + rch;

    f32x4 acc[8][4];
#pragma unroll
    for (int m = 0; m < 8; ++m)
#pragma unroll
        for (int n = 0; n < 4; ++n)
            acc[m][n] = {0.0f, 0.0f, 0.0f, 0.0f};

    auto stage = [&](int b, int kt) {
        const size_t ko = (size_t)kt * BK;
#pragma unroll
        for (int i = 0; i < 2; ++i) {
            GLOAD16(Abase + aoff + (size_t)i * 128 * KTOT + ko, &Asm[b][i * 4096 + ldst]);
            GLOAD16(Bbase + aoff + (size_t)i * 128 * KTOT + ko, &Bsm[b][i * 4096 + ldst]);
        }
    };

    // prologue: 3 tiles in flight (12 loads/wave); confirm tile 0 (oldest 4)
    stage(0, 0);
    stage(1, 1);
    stage(2, 2);
    VMCNT(8);
    BAR();

    // pipeline invariants per iter t:
    //  - reads buf[t&3] (tile t confirmed by prev iter's vmcnt + barrier)
    //  - stages tile t+3 into buf[(t+3)&3] = buffer read at iter t-1 (WAR-safe:
    //    those reads completed before the iter t-1 end barrier via MFMA data deps)
    //  - vmcnt(8) leaves tiles t+2, t+3 in flight across the barrier (T4)
#pragma unroll
    for (int t = 0; t < NSTEP; ++t) {
        if (t + 3 < NSTEP) stage((t + 3) & 3, t + 3);
        const int b = t & 3;
        bf16x8 af[8], bfr[4];
#pragma unroll
        for (int n = 0; n < 4; ++n)
            bfr[n] = __builtin_bit_cast(bf16x8, *reinterpret_cast<const u32x4*>(&Bsm[b][bridx[n]]));
#pragma unroll
        for (int m = 0; m < 8; ++m)
            af[m] = __builtin_bit_cast(bf16x8, *reinterpret_cast<const u32x4*>(&Asm[b][aridx[m]]));
        __builtin_amdgcn_s_setprio(1);
#pragma unroll
        for (int m = 0; m < 8; ++m)
#pragma unroll
            for (int n = 0; n < 4; ++n)
                acc[m][n] = __builtin_amdgcn_mfma_f32_16x16x32_bf16(af[m], bfr[n], acc[m][n], 0, 0, 0);
        __builtin_amdgcn_s_setprio(0);
        if (t < NSTEP - 3)       VMCNT(8);
        else if (t == NSTEP - 3) VMCNT(4);
        else if (t == NSTEP - 2) VMCNT(0);
        if (t < NSTEP - 1) BAR();
    }

    // epilogue: C/D layout col=lane&15, row=(lane>>4)*4+q ; store valid rows only
    float bv[4];
#pragma unroll
    for (int n = 0; n < 4; ++n)
        bv[n] = bias[n0 + wn * 64 + n * 16 + lr];

#pragma unroll
    for (int m = 0; m < 8; ++m) {
#pragma unroll
        for (int q = 0; q < 4; ++q) {
            const size_t row = m0 + wm * 128 + m * 16 + g4 * 4 + q;
            if (valid[row]) {
                const size_t ro = row * NTOT + n0 + wn * 64 + lr;
#pragma unroll
                for (int n = 0; n < 4; ++n)
                    out[ro + n * 16] = fmaxf(acc[m][n][q] + bv[n], 0.0f);
            }
        }
    }
}

// ================= fallback path (ws too small; round-1 kernels) =================
#define FBM 128
#define FBN 128
#define FBK 32

__global__ __launch_bounds__(256) void valid_kernel(const int* __restrict__ adj,
                                                    unsigned char* __restrict__ valid) {
    const int row  = blockIdx.x * 4 + (threadIdx.x >> 6);
    const int lane = threadIdx.x & 63;
    const int2 v = reinterpret_cast<const int2*>(adj)[(size_t)row * 64 + lane];
    const int anyv = __any((v.x >= 0) || (v.y >= 0));
    if (lane == 0) valid[row] = anyv ? 1 : 0;
}

__global__ __launch_bounds__(256) void gemm_fb(const float* __restrict__ A,
                                               const unsigned short* __restrict__ Bt,
                                               const float* __restrict__ bias,
                                               const unsigned char* __restrict__ valid,
                                               float* __restrict__ out) {
    __shared__ __align__(16) unsigned short Asm[2][FBM * FBK];
    __shared__ __align__(16) unsigned short Bsm[2][FBN * FBK];
    const int tid = threadIdx.x;
    const int bm = blockIdx.x >> 3;
    const int bn = blockIdx.x & 7;
    const size_t m0 = (size_t)bm * FBM;
    const int n0 = bn * FBN;
    const int ja = tid & 7, ra0 = tid >> 3;
    const int jb = tid & 3, rb0 = tid >> 2;
    const int wv = tid >> 6, wr = wv >> 1, wc = wv & 1;
    const int lane = tid & 63, lr = lane & 15, g = lane >> 4;
    f32x4 acc[4][4];
#pragma unroll
    for (int m = 0; m < 4; ++m)
#pragma unroll
        for (int n = 0; n < 4; ++n) acc[m][n] = {0.f, 0.f, 0.f, 0.f};
    int awidx[4], bwidx[2], aridx[4], bridx[4];
#pragma unroll
    for (int t = 0; t < 4; ++t) {
        const int row = ra0 + t * 32;
        awidx[t] = row * 32 + (((ja >> 1) ^ ((row >> 1) & 3)) * 8) + (ja & 1) * 4;
    }
#pragma unroll
    for (int t = 0; t < 2; ++t) {
        const int row = rb0 + t * 64;
        bwidx[t] = row * 32 + ((jb ^ ((row >> 1) & 3)) * 8);
    }
#pragma unroll
    for (int m = 0; m < 4; ++m) {
        const int row = wr * 64 + m * 16 + lr;
        aridx[m] = row * 32 + ((g ^ ((row >> 1) & 3)) * 8);
    }
#pragma unroll
    for (int n = 0; n < 4; ++n) {
        const int row = wc * 64 + n * 16 + lr;
        bridx[n] = row * 32 + ((g ^ ((row >> 1) & 3)) * 8);
    }
    const int NT = KTOT / FBK;
    f32x4 areg[4];
    u32x4 breg[2];
#pragma unroll
    for (int t = 0; t < 4; ++t)
        areg[t] = reinterpret_cast<const f32x4*>(A + (m0 + ra0 + t * 32) * KTOT)[ja];
#pragma unroll
    for (int t = 0; t < 2; ++t)
        breg[t] = reinterpret_cast<const u32x4*>(Bt + (size_t)(n0 + rb0 + t * 64) * KTOT)[jb];
#pragma unroll
    for (int t = 0; t < 4; ++t) {
        unsigned long long w = (unsigned long long)f2bf(areg[t][0]) |
                               ((unsigned long long)f2bf(areg[t][1]) << 16) |
                               ((unsigned long long)f2bf(areg[t][2]) << 32) |
                               ((unsigned long long)f2bf(areg[t][3]) << 48);
        *reinterpret_cast<unsigned long long*>(&Asm[0][awidx[t]]) = w;
    }
#pragma unroll
    for (int t = 0; t < 2; ++t) *reinterpret_cast<u32x4*>(&Bsm[0][bwidx[t]]) = breg[t];
    int cur = 0;
    for (int kt = 0; kt < NT; ++kt) {
        const bool more = (kt + 1) < NT;
        if (more) {
            const int koff = (kt + 1) * FBK;
#pragma unroll
            for (int t = 0; t < 4; ++t)
                areg[t] = reinterpret_cast<const f32x4*>(A + (m0 + ra0 + t * 32) * KTOT + koff)[ja];
#pragma unroll
            for (int t = 0; t < 2; ++t)
                breg[t] = reinterpret_cast<const u32x4*>(Bt + (size_t)(n0 + rb0 + t * 64) * KTOT + koff)[jb];
        }
        __syncthreads();
        bf16x8 af[4], bfr[4];
#pragma unroll
        for (int m = 0; m < 4; ++m)
            af[m] = __builtin_bit_cast(bf16x8, *reinterpret_cast<const u32x4*>(&Asm[cur][aridx[m]]));
#pragma unroll
        for (int n = 0; n < 4; ++n)
            bfr[n] = __builtin_bit_cast(bf16x8, *reinterpret_cast<const u32x4*>(&Bsm[cur][bridx[n]]));
#pragma unroll
        for (int m = 0; m < 4; ++m)
#pragma unroll
            for (int n = 0; n < 4; ++n)
                acc[m][n] = __builtin_amdgcn_mfma_f32_16x16x32_bf16(af[m], bfr[n], acc[m][n], 0, 0, 0);
        if (more) {
            const int nxt = cur ^ 1;
#pragma unroll
            for (int t = 0; t < 4; ++t) {
                unsigned long long w = (unsigned long long)f2bf(areg[t][0]) |
                                       ((unsigned long long)f2bf(areg[t][1]) << 16) |
                                       ((unsigned long long)f2bf(areg[t][2]) << 32) |
                                       ((unsigned long long)f2bf(areg[t][3]) << 48);
                *reinterpret_cast<unsigned long long*>(&Asm[nxt][awidx[t]]) = w;
            }
#pragma unroll
            for (int t = 0; t < 2; ++t) *reinterpret_cast<u32x4*>(&Bsm[nxt][bwidx[t]]) = breg[t];
        }
        cur ^= 1;
    }
    float bv[4];
#pragma unroll
    for (int n = 0; n < 4; ++n) bv[n] = bias[n0 + wc * 64 + n * 16 + lr];
#pragma unroll
    for (int m = 0; m < 4; ++m) {
#pragma unroll
        for (int q = 0; q < 4; ++q) {
            const size_t row = m0 + wr * 64 + m * 16 + g * 4 + q;
            const bool v = valid[row] != 0;
            const size_t ro = row * (size_t)NTOT;
#pragma unroll
            for (int n = 0; n < 4; ++n) {
                const int col = n0 + wc * 64 + n * 16 + lr;
                out[ro + col] = v ? fmaxf(acc[m][n][q] + bv[n], 0.0f) : A[ro + col];
            }
        }
    }
}

extern "C" void kernel_launch(void* const* d_in, const int* in_sizes, int n_in,
                              void* d_out, int out_size, void* d_ws, size_t ws_size,
                              hipStream_t stream) {
    const int*   adj  = (const int*)d_in[0];
    const float* feat = (const float*)d_in[1];
    const float* kern = (const float*)d_in[2];
    const float* bias = (const float*)d_in[3];
    float* out = (float*)d_out;

    unsigned short* kT    = (unsigned short*)d_ws;                             // 2 MB
    unsigned char*  valid = (unsigned char*)d_ws + 2 * 1024 * 1024;            // 64 KB
    unsigned short* abf   = (unsigned short*)((char*)d_ws + 2 * 1024 * 1024 + 65536);

    const size_t need = 2ull * 1024 * 1024 + 65536 + (size_t)MTOT * KTOT * 2;

    transposeB_kernel<<<(KTOT / 32) * (NTOT / 32), 256, 0, stream>>>(kern, kT);
    if (ws_size >= need) {
        prep_kernel<<<MTOT / 4, 256, 0, stream>>>(adj, feat, abf, valid, out);
        gemm_kernel<<<(MTOT / BM) * (NTOT / BN), 512, 0, stream>>>(abf, kT, bias, valid, out);
    } else {
        valid_kernel<<<MTOT / 4, 256, 0, stream>>>(adj, valid);
        gemm_fb<<<(MTOT / FBM) * (NTOT / FBN), 256, 0, stream>>>(feat, kT, bias, valid, out);
    }
}